// Round 1
// baseline (931.784 us; speedup 1.0000x reference)
//
#include <hip/hip_runtime.h>
#include <hip/hip_bf16.h>
#include <math.h>

#define IN_DIM 128
#define OUT_DIM 128

__device__ inline float readlane_f(float v, int l) {
    return __uint_as_float(__builtin_amdgcn_readlane(__float_as_uint(v), l));
}

// ---------------------------------------------------------------------------
// K1: x = input @ W  (fp32 vector GEMM), fused epilogue s_src = x@a[:d], s_dst = x@a[d:]
// 256 threads = 4 waves; each wave computes 32 rows, 4 rows concurrently.
// W staged in LDS (64 KB); lane owns output cols {2*lane, 2*lane+1}.
// ---------------------------------------------------------------------------
__global__ __launch_bounds__(256) void gemm_xw_kernel(
    const float* __restrict__ in, const float* __restrict__ W,
    const float* __restrict__ a, float* __restrict__ x,
    float* __restrict__ ssrc, float* __restrict__ sdst, int N)
{
    __shared__ float Wl[IN_DIM * OUT_DIM];
    {
        const float4* Wg = (const float4*)W;
        float4* Ws = (float4*)Wl;
        for (int idx = threadIdx.x; idx < IN_DIM * OUT_DIM / 4; idx += 256)
            Ws[idx] = Wg[idx];
    }
    const int lane = threadIdx.x & 63;
    const int wave = threadIdx.x >> 6;
    const float a_s0 = a[2 * lane], a_s1 = a[2 * lane + 1];
    const float a_d0 = a[OUT_DIM + 2 * lane], a_d1 = a[OUT_DIM + 2 * lane + 1];
    __syncthreads();

    const int WAVE_ROWS = 32;
    const long long base = ((long long)blockIdx.x * 4 + wave) * WAVE_ROWS;
    const float2* W2 = (const float2*)Wl;

    for (int rr = 0; rr < WAVE_ROWS; rr += 4) {
        long long row[4];
        float ra[4], rb[4];
#pragma unroll
        for (int q = 0; q < 4; q++) {
            long long r = base + rr + q;
            row[q] = r;
            long long rc = (r < N) ? r : (N - 1);
            ra[q] = in[rc * IN_DIM + lane];
            rb[q] = in[rc * IN_DIM + 64 + lane];
        }
        float acc[4][2] = {{0.f, 0.f}, {0.f, 0.f}, {0.f, 0.f}, {0.f, 0.f}};
#pragma unroll
        for (int k = 0; k < 64; k++) {
            float2 w = W2[k * 64 + lane];
#pragma unroll
            for (int q = 0; q < 4; q++) {
                float ik = readlane_f(ra[q], k);
                acc[q][0] += ik * w.x;
                acc[q][1] += ik * w.y;
            }
        }
#pragma unroll
        for (int k = 0; k < 64; k++) {
            float2 w = W2[(64 + k) * 64 + lane];
#pragma unroll
            for (int q = 0; q < 4; q++) {
                float ik = readlane_f(rb[q], k);
                acc[q][0] += ik * w.x;
                acc[q][1] += ik * w.y;
            }
        }
#pragma unroll
        for (int q = 0; q < 4; q++) {
            if (row[q] < N) {
                *(float2*)(x + row[q] * OUT_DIM + 2 * lane) =
                    make_float2(acc[q][0], acc[q][1]);
                float ps = acc[q][0] * a_s0 + acc[q][1] * a_s1;
                float pd = acc[q][0] * a_d0 + acc[q][1] * a_d1;
#pragma unroll
                for (int off = 32; off; off >>= 1) {
                    ps += __shfl_xor(ps, off);
                    pd += __shfl_xor(pd, off);
                }
                if (lane == 0) {
                    ssrc[row[q]] = ps;
                    sdst[row[q]] = pd;
                }
            }
        }
    }
}

// ---------------------------------------------------------------------------
// K2: histogram of head nodes
// ---------------------------------------------------------------------------
__global__ void hist_kernel(const int* __restrict__ triple,
                            int* __restrict__ counts, int E)
{
    int i = blockIdx.x * blockDim.x + threadIdx.x;
    if (i < E) atomicAdd(&counts[triple[3 * i]], 1);
}

// ---------------------------------------------------------------------------
// K3: single-workgroup exclusive scan of counts -> start offsets (N+1)
// ---------------------------------------------------------------------------
__global__ __launch_bounds__(1024) void scan_kernel(
    const int* __restrict__ counts, int* __restrict__ startp, int N)
{
    __shared__ int ps[1024];
    const int tid = threadIdx.x;
    const int chunk = (N + 1023) >> 10;
    const int lo = tid * chunk;
    const int hi = min(lo + chunk, N);
    int s = 0;
    for (int i = lo; i < hi; i++) s += counts[i];
    ps[tid] = s;
    __syncthreads();
    for (int off = 1; off < 1024; off <<= 1) {
        int v = 0;
        if (tid >= off) v = ps[tid - off];
        __syncthreads();
        if (tid >= off) ps[tid] += v;
        __syncthreads();
    }
    int running = (tid == 0) ? 0 : ps[tid - 1];
    for (int i = lo; i < hi; i++) {
        startp[i] = running;
        running += counts[i];
    }
    if (tid == 1023) startp[N] = running;
}

// ---------------------------------------------------------------------------
// K4: scatter edges into CSR buckets. atomicAdd turns startp[i] into end-of-
// bucket-i, so downstream lo = (i? startp[i-1]:0), hi = startp[i].
// ---------------------------------------------------------------------------
__global__ void scatter_kernel(const int* __restrict__ triple,
                               int* __restrict__ startp,
                               int* __restrict__ edge_t, int E)
{
    int i = blockIdx.x * blockDim.x + threadIdx.x;
    if (i < E) {
        int h = triple[3 * i];
        int t = triple[3 * i + 2];
        int pos = atomicAdd(&startp[h], 1);
        edge_t[pos] = t;
    }
}

// ---------------------------------------------------------------------------
// K5: per-node softmax-attention aggregation. One wave per node; lane owns
// dims {2*lane, 2*lane+1}. Three passes over the node's edge list:
// max -> denom -> weighted gather of x[t]. Epilogue: elu(agg + x[i]).
// ---------------------------------------------------------------------------
__global__ __launch_bounds__(256) void aggregate_kernel(
    const float* __restrict__ x, const float* __restrict__ ssrc,
    const float* __restrict__ sdst, const int* __restrict__ endp,
    const int* __restrict__ edge_t, float* __restrict__ out, int N)
{
    const int wave = threadIdx.x >> 6;
    const int lane = threadIdx.x & 63;
    const int i = blockIdx.x * 4 + wave;
    if (i >= N) return;
    const int lo = (i == 0) ? 0 : endp[i - 1];
    const int hi = endp[i];
    const float si = ssrc[i];

    // pass A: segment max
    float m = -INFINITY;
    for (int j = lo + lane; j < hi; j += 64) {
        int t = edge_t[j];
        float e = si + sdst[t];
        e = (e > 0.f) ? e : 0.2f * e;
        m = fmaxf(m, e);
    }
#pragma unroll
    for (int off = 32; off; off >>= 1) m = fmaxf(m, __shfl_xor(m, off));

    // pass B: denom
    float den = 0.f;
    for (int j = lo + lane; j < hi; j += 64) {
        int t = edge_t[j];
        float e = si + sdst[t];
        e = (e > 0.f) ? e : 0.2f * e;
        den += __expf(e - m);
    }
#pragma unroll
    for (int off = 32; off; off >>= 1) den += __shfl_xor(den, off);
    const float invden = (hi > lo) ? 1.f / den : 0.f;

    // pass C: weighted gather-accumulate
    float acc0 = 0.f, acc1 = 0.f;
    for (int j = lo; j < hi; j++) {
        int t = edge_t[j];
        float e = si + sdst[t];
        e = (e > 0.f) ? e : 0.2f * e;
        float w = __expf(e - m) * invden;
        float2 v = *(const float2*)(x + (size_t)t * OUT_DIM + 2 * lane);
        acc0 += w * v.x;
        acc1 += w * v.y;
    }

    float2 xi = *(const float2*)(x + (size_t)i * OUT_DIM + 2 * lane);
    float o0 = acc0 + xi.x;
    float o1 = acc1 + xi.y;
    o0 = (o0 > 0.f) ? o0 : __expf(o0) - 1.f;
    o1 = (o1 > 0.f) ? o1 : __expf(o1) - 1.f;
    *(float2*)(out + (size_t)i * OUT_DIM + 2 * lane) = make_float2(o0, o1);
}

// ---------------------------------------------------------------------------
extern "C" void kernel_launch(void* const* d_in, const int* in_sizes, int n_in,
                              void* d_out, int out_size, void* d_ws, size_t ws_size,
                              hipStream_t stream)
{
    const float* input  = (const float*)d_in[0];
    const float* W      = (const float*)d_in[1];
    const float* a      = (const float*)d_in[2];
    const int*   triple = (const int*)d_in[3];
    const int N = in_sizes[0] / IN_DIM;
    const int E = in_sizes[3] / 3;
    float* out = (float*)d_out;

    // workspace layout
    float* x     = (float*)d_ws;          // N*128 floats
    float* ssrc  = x + (size_t)N * OUT_DIM;
    float* sdst  = ssrc + N;
    int*   counts = (int*)(sdst + N);     // N ints
    int*   startp = counts + N;           // N+1 ints
    int*   edge_t = startp + N + 1;       // E ints

    hipMemsetAsync(counts, 0, (size_t)N * sizeof(int), stream);

    gemm_xw_kernel<<<(N + 127) / 128, 256, 0, stream>>>(input, W, a, x, ssrc, sdst, N);
    hist_kernel<<<(E + 255) / 256, 256, 0, stream>>>(triple, counts, E);
    scan_kernel<<<1, 1024, 0, stream>>>(counts, startp, N);
    scatter_kernel<<<(E + 255) / 256, 256, 0, stream>>>(triple, startp, edge_t, E);
    aggregate_kernel<<<(N + 3) / 4, 256, 0, stream>>>(x, ssrc, sdst, startp, edge_t, out, N);
}

// Round 2
// 570.516 us; speedup vs baseline: 1.6332x; 1.6332x over previous
//
#include <hip/hip_runtime.h>
#include <hip/hip_bf16.h>
#include <math.h>

#define IN_DIM 128
#define OUT_DIM 128
#define BM 64

typedef short bf16x8s __attribute__((ext_vector_type(8)));
typedef float f32x4 __attribute__((ext_vector_type(4)));

__device__ inline unsigned int rne_hi(float f) {
    unsigned int u = __float_as_uint(f);
    return u + 0x7fffu + ((u >> 16) & 1u);   // high 16 bits = RNE bf16
}
__device__ inline unsigned int pack_bf16x2(float lo, float hi) {
    return (rne_hi(lo) >> 16) | (rne_hi(hi) & 0xffff0000u);
}

// ---------------------------------------------------------------------------
// K0: transpose + convert W (128x128 fp32, row-major [k][c]) -> Wt bf16 [c][k]
// ---------------------------------------------------------------------------
__global__ void wt_kernel(const float* __restrict__ W, unsigned short* __restrict__ Wt)
{
    int k = blockIdx.x;          // 128 blocks
    int c = threadIdx.x;         // 128 threads, coalesced read of row k
    float v = W[k * OUT_DIM + c];
    Wt[c * IN_DIM + k] = (unsigned short)(rne_hi(v) >> 16);
}

// ---------------------------------------------------------------------------
// K1: x = input @ W via bf16 MFMA (fp32 accum), fused s_src/s_dst epilogue.
// Block = 256 thr (4 waves). Tile: 64 rows x 128 cols. K=128 in 4 MFMA steps.
// ---------------------------------------------------------------------------
__global__ __launch_bounds__(256) void gemm_xw_kernel(
    const float* __restrict__ in, const unsigned short* __restrict__ WtG,
    const float* __restrict__ a, float* __restrict__ x,
    float* __restrict__ ssrc, float* __restrict__ sdst, int N)
{
    __shared__ unsigned short Al[BM][IN_DIM + 8];      // +8 pad: bank spread
    __shared__ unsigned short Wl[OUT_DIM][IN_DIM + 8];

    const int tid  = threadIdx.x;
    const int lane = tid & 63;
    const int wave = tid >> 6;
    const int rl   = lane & 15;     // row (A) / col (B) within 16
    const int rgrp = lane >> 4;     // k-group 0..3

    // ---- stage Wt (bf16) into LDS: 128 rows, 2 threads/row x 64 cols ----
    {
        int r = tid >> 1, c0 = (tid & 1) * 64;
        const uint4* src = (const uint4*)(WtG + r * IN_DIM + c0);
        uint4* dst = (uint4*)&Wl[r][c0];
#pragma unroll
        for (int u = 0; u < 8; u++) dst[u] = src[u];
    }

    // ---- stage A tile: 64 rows x 128 k, fp32 -> bf16 ----
    const long long rowbase = (long long)blockIdx.x * BM;
    {
#pragma unroll
        for (int u = 0; u < 8; u++) {
            int idx = u * 256 + tid;          // float4-group index
            int r = idx >> 5;                 // 32 float4 per row
            int c = (idx & 31) * 4;
            long long gr = rowbase + r;
            if (gr >= N) gr = N - 1;
            float4 v = *(const float4*)(in + gr * IN_DIM + c);
            *(uint2*)&Al[r][c] = make_uint2(pack_bf16x2(v.x, v.y), pack_bf16x2(v.z, v.w));
        }
    }
    __syncthreads();

    // ---- MFMA: wave handles rows [wave*16, wave*16+16), all 128 cols ----
    f32x4 acc[8] = {};
#pragma unroll
    for (int ks = 0; ks < 4; ks++) {
        bf16x8s af = *(const bf16x8s*)&Al[wave * 16 + rl][ks * 32 + rgrp * 8];
#pragma unroll
        for (int cb = 0; cb < 8; cb++) {
            bf16x8s bf = *(const bf16x8s*)&Wl[cb * 16 + rl][ks * 32 + rgrp * 8];
            acc[cb] = __builtin_amdgcn_mfma_f32_16x16x32_bf16(af, bf, acc[cb], 0, 0, 0);
        }
    }

    // ---- epilogue: write x, fused scores ----
    float a_sv[8], a_dv[8];
#pragma unroll
    for (int cb = 0; cb < 8; cb++) {
        a_sv[cb] = a[rl + 16 * cb];
        a_dv[cb] = a[OUT_DIM + rl + 16 * cb];
    }
#pragma unroll
    for (int r = 0; r < 4; r++) {
        long long grow = rowbase + wave * 16 + rgrp * 4 + r;
        float ps = 0.f, pd = 0.f;
#pragma unroll
        for (int cb = 0; cb < 8; cb++) {
            float v = acc[cb][r];
            if (grow < N) x[grow * OUT_DIM + rl + 16 * cb] = v;
            ps += v * a_sv[cb];
            pd += v * a_dv[cb];
        }
#pragma unroll
        for (int off = 1; off < 16; off <<= 1) {
            ps += __shfl_xor(ps, off);
            pd += __shfl_xor(pd, off);
        }
        if (rl == 0 && grow < N) { ssrc[grow] = ps; sdst[grow] = pd; }
    }
}

// ---------------------------------------------------------------------------
// K2: histogram of head nodes
// ---------------------------------------------------------------------------
__global__ void hist_kernel(const int* __restrict__ triple,
                            int* __restrict__ counts, int E)
{
    int i = blockIdx.x * blockDim.x + threadIdx.x;
    if (i < E) atomicAdd(&counts[triple[3 * i]], 1);
}

// ---------------------------------------------------------------------------
// K3: single-workgroup exclusive scan of counts -> start offsets (N+1)
// ---------------------------------------------------------------------------
__global__ __launch_bounds__(1024) void scan_kernel(
    const int* __restrict__ counts, int* __restrict__ startp, int N)
{
    __shared__ int ps[1024];
    const int tid = threadIdx.x;
    const int chunk = (N + 1023) >> 10;
    const int lo = tid * chunk;
    const int hi = min(lo + chunk, N);
    int s = 0;
    for (int i = lo; i < hi; i++) s += counts[i];
    ps[tid] = s;
    __syncthreads();
    for (int off = 1; off < 1024; off <<= 1) {
        int v = 0;
        if (tid >= off) v = ps[tid - off];
        __syncthreads();
        if (tid >= off) ps[tid] += v;
        __syncthreads();
    }
    int running = (tid == 0) ? 0 : ps[tid - 1];
    for (int i = lo; i < hi; i++) {
        startp[i] = running;
        running += counts[i];
    }
    if (tid == 1023) startp[N] = running;
}

// ---------------------------------------------------------------------------
// K4: scatter edges into CSR buckets (startp[i] becomes end-of-bucket-i)
// ---------------------------------------------------------------------------
__global__ void scatter_kernel(const int* __restrict__ triple,
                               int* __restrict__ startp,
                               int* __restrict__ edge_t, int E)
{
    int i = blockIdx.x * blockDim.x + threadIdx.x;
    if (i < E) {
        int h = triple[3 * i];
        int t = triple[3 * i + 2];
        int pos = atomicAdd(&startp[h], 1);
        edge_t[pos] = t;
    }
}

// ---------------------------------------------------------------------------
// K5: per-node softmax-attention aggregation (one wave per node)
// ---------------------------------------------------------------------------
__global__ __launch_bounds__(256) void aggregate_kernel(
    const float* __restrict__ x, const float* __restrict__ ssrc,
    const float* __restrict__ sdst, const int* __restrict__ endp,
    const int* __restrict__ edge_t, float* __restrict__ out, int N)
{
    const int wave = threadIdx.x >> 6;
    const int lane = threadIdx.x & 63;
    const int i = blockIdx.x * 4 + wave;
    if (i >= N) return;
    const int lo = (i == 0) ? 0 : endp[i - 1];
    const int hi = endp[i];
    const float si = ssrc[i];

    float m = -INFINITY;
    for (int j = lo + lane; j < hi; j += 64) {
        int t = edge_t[j];
        float e = si + sdst[t];
        e = (e > 0.f) ? e : 0.2f * e;
        m = fmaxf(m, e);
    }
#pragma unroll
    for (int off = 32; off; off >>= 1) m = fmaxf(m, __shfl_xor(m, off));

    float den = 0.f;
    for (int j = lo + lane; j < hi; j += 64) {
        int t = edge_t[j];
        float e = si + sdst[t];
        e = (e > 0.f) ? e : 0.2f * e;
        den += __expf(e - m);
    }
#pragma unroll
    for (int off = 32; off; off >>= 1) den += __shfl_xor(den, off);
    const float invden = (hi > lo) ? 1.f / den : 0.f;

    float acc0 = 0.f, acc1 = 0.f;
    for (int j = lo; j < hi; j++) {
        int t = edge_t[j];
        float e = si + sdst[t];
        e = (e > 0.f) ? e : 0.2f * e;
        float w = __expf(e - m) * invden;
        float2 v = *(const float2*)(x + (size_t)t * OUT_DIM + 2 * lane);
        acc0 += w * v.x;
        acc1 += w * v.y;
    }

    float2 xi = *(const float2*)(x + (size_t)i * OUT_DIM + 2 * lane);
    float o0 = acc0 + xi.x;
    float o1 = acc1 + xi.y;
    o0 = (o0 > 0.f) ? o0 : __expf(o0) - 1.f;
    o1 = (o1 > 0.f) ? o1 : __expf(o1) - 1.f;
    *(float2*)(out + (size_t)i * OUT_DIM + 2 * lane) = make_float2(o0, o1);
}

// ---------------------------------------------------------------------------
extern "C" void kernel_launch(void* const* d_in, const int* in_sizes, int n_in,
                              void* d_out, int out_size, void* d_ws, size_t ws_size,
                              hipStream_t stream)
{
    const float* input  = (const float*)d_in[0];
    const float* W      = (const float*)d_in[1];
    const float* a      = (const float*)d_in[2];
    const int*   triple = (const int*)d_in[3];
    const int N = in_sizes[0] / IN_DIM;
    const int E = in_sizes[3] / 3;
    float* out = (float*)d_out;

    // workspace layout (x first keeps 16B alignment for Wt uint4 reads)
    float* x            = (float*)d_ws;                 // N*128 floats
    unsigned short* Wt  = (unsigned short*)(x + (size_t)N * OUT_DIM); // 16384 u16
    float* ssrc         = (float*)(Wt + IN_DIM * OUT_DIM);
    float* sdst         = ssrc + N;
    int*   counts       = (int*)(sdst + N);             // N ints
    int*   startp       = counts + N;                   // N+1 ints
    int*   edge_t       = startp + N + 1;               // E ints

    hipMemsetAsync(counts, 0, (size_t)N * sizeof(int), stream);

    wt_kernel<<<IN_DIM, OUT_DIM, 0, stream>>>(W, Wt);
    gemm_xw_kernel<<<(N + BM - 1) / BM, 256, 0, stream>>>(input, Wt, a, x, ssrc, sdst, N);
    hist_kernel<<<(E + 255) / 256, 256, 0, stream>>>(triple, counts, E);
    scan_kernel<<<1, 1024, 0, stream>>>(counts, startp, N);
    scatter_kernel<<<(E + 255) / 256, 256, 0, stream>>>(triple, startp, edge_t, E);
    aggregate_kernel<<<(N + 3) / 4, 256, 0, stream>>>(x, ssrc, sdst, startp, edge_t, out, N);
}

// Round 3
// 313.375 us; speedup vs baseline: 2.9734x; 1.8206x over previous
//
#include <hip/hip_runtime.h>
#include <hip/hip_bf16.h>
#include <math.h>

#define IN_DIM 128
#define OUT_DIM 128
#define BM 64

typedef short bf16x8s __attribute__((ext_vector_type(8)));
typedef float f32x4 __attribute__((ext_vector_type(4)));
typedef unsigned short u16;
typedef unsigned short u16x8 __attribute__((ext_vector_type(8)));

__device__ inline unsigned int rne_hi(float f) {
    unsigned int u = __float_as_uint(f);
    return u + 0x7fffu + ((u >> 16) & 1u);   // high 16 bits = RNE bf16
}
__device__ inline unsigned int pack_bf16x2(float lo, float hi) {
    return (rne_hi(lo) >> 16) | (rne_hi(hi) & 0xffff0000u);
}
__device__ inline float bf2f(u16 v) { return __uint_as_float(((unsigned)v) << 16); }

// ---------------------------------------------------------------------------
// K0: transpose + convert W [k][c] fp32 -> Wt bf16 [c][k]
// ---------------------------------------------------------------------------
__global__ void wt_kernel(const float* __restrict__ W, u16* __restrict__ Wt)
{
    int k = blockIdx.x;
    int c = threadIdx.x;
    float v = W[k * OUT_DIM + c];
    Wt[c * IN_DIM + k] = (u16)(rne_hi(v) >> 16);
}

// ---------------------------------------------------------------------------
// K1: x = input @ W via bf16 MFMA; writes x as bf16; fused s_src/s_dst.
// ---------------------------------------------------------------------------
__global__ __launch_bounds__(256) void gemm_xw_kernel(
    const float* __restrict__ in, const u16* __restrict__ WtG,
    const float* __restrict__ a, u16* __restrict__ xbf,
    float* __restrict__ ssrc, float* __restrict__ sdst, int N)
{
    __shared__ u16 Al[BM][IN_DIM + 8];
    __shared__ u16 Wl[OUT_DIM][IN_DIM + 8];

    const int tid  = threadIdx.x;
    const int lane = tid & 63;
    const int wave = tid >> 6;
    const int rl   = lane & 15;
    const int rgrp = lane >> 4;

    {
        int r = tid >> 1, c0 = (tid & 1) * 64;
        const uint4* src = (const uint4*)(WtG + r * IN_DIM + c0);
        uint4* dst = (uint4*)&Wl[r][c0];
#pragma unroll
        for (int u = 0; u < 8; u++) dst[u] = src[u];
    }
    const long long rowbase = (long long)blockIdx.x * BM;
    {
#pragma unroll
        for (int u = 0; u < 8; u++) {
            int idx = u * 256 + tid;
            int r = idx >> 5;
            int c = (idx & 31) * 4;
            long long gr = rowbase + r;
            if (gr >= N) gr = N - 1;
            float4 v = *(const float4*)(in + gr * IN_DIM + c);
            *(uint2*)&Al[r][c] = make_uint2(pack_bf16x2(v.x, v.y), pack_bf16x2(v.z, v.w));
        }
    }
    __syncthreads();

    f32x4 acc[8] = {};
#pragma unroll
    for (int ks = 0; ks < 4; ks++) {
        bf16x8s af = *(const bf16x8s*)&Al[wave * 16 + rl][ks * 32 + rgrp * 8];
#pragma unroll
        for (int cb = 0; cb < 8; cb++) {
            bf16x8s bf = *(const bf16x8s*)&Wl[cb * 16 + rl][ks * 32 + rgrp * 8];
            acc[cb] = __builtin_amdgcn_mfma_f32_16x16x32_bf16(af, bf, acc[cb], 0, 0, 0);
        }
    }

    float a_sv[8], a_dv[8];
#pragma unroll
    for (int cb = 0; cb < 8; cb++) {
        a_sv[cb] = a[rl + 16 * cb];
        a_dv[cb] = a[OUT_DIM + rl + 16 * cb];
    }
#pragma unroll
    for (int r = 0; r < 4; r++) {
        long long grow = rowbase + wave * 16 + rgrp * 4 + r;
        float ps = 0.f, pd = 0.f;
#pragma unroll
        for (int cb = 0; cb < 8; cb++) {
            float v = acc[cb][r];
            if (grow < N) xbf[grow * OUT_DIM + rl + 16 * cb] = (u16)(rne_hi(v) >> 16);
            ps += v * a_sv[cb];
            pd += v * a_dv[cb];
        }
#pragma unroll
        for (int off = 1; off < 16; off <<= 1) {
            ps += __shfl_xor(ps, off);
            pd += __shfl_xor(pd, off);
        }
        if (rl == 0 && grow < N) { ssrc[grow] = ps; sdst[grow] = pd; }
    }
}

// ---------------------------------------------------------------------------
// K2: histogram of head nodes
// ---------------------------------------------------------------------------
__global__ void hist_kernel(const int* __restrict__ triple,
                            int* __restrict__ counts, int E)
{
    int i = blockIdx.x * blockDim.x + threadIdx.x;
    if (i < E) atomicAdd(&counts[triple[3 * i]], 1);
}

// ---------------------------------------------------------------------------
// K3a/b/c: multi-block exclusive scan of counts -> startp
// ---------------------------------------------------------------------------
__global__ __launch_bounds__(1024) void scan_part(const int* __restrict__ counts,
                                                  int* __restrict__ bsum, int N)
{
    __shared__ int ws[16];
    int tid = threadIdx.x;
    int idx = blockIdx.x * 1024 + tid;
    int v = (idx < N) ? counts[idx] : 0;
#pragma unroll
    for (int off = 32; off; off >>= 1) v += __shfl_xor(v, off);
    if ((tid & 63) == 0) ws[tid >> 6] = v;
    __syncthreads();
    if (tid == 0) {
        int s = 0;
#pragma unroll
        for (int w = 0; w < 16; w++) s += ws[w];
        bsum[blockIdx.x] = s;
    }
}

__global__ void scan_top(int* __restrict__ bsum, int nb)
{
    if (threadIdx.x == 0) {
        int s = 0;
        for (int i = 0; i < nb; i++) { int c = bsum[i]; bsum[i] = s; s += c; }
    }
}

__global__ __launch_bounds__(1024) void scan_final(const int* __restrict__ counts,
                                                   const int* __restrict__ bsum,
                                                   int* __restrict__ startp, int N)
{
    __shared__ int ps[1024];
    int tid = threadIdx.x;
    int idx = blockIdx.x * 1024 + tid;
    int v = (idx < N) ? counts[idx] : 0;
    ps[tid] = v;
    __syncthreads();
#pragma unroll
    for (int off = 1; off < 1024; off <<= 1) {
        int t = 0;
        if (tid >= off) t = ps[tid - off];
        __syncthreads();
        if (tid >= off) ps[tid] += t;
        __syncthreads();
    }
    if (idx < N) startp[idx] = (tid ? ps[tid - 1] : 0) + bsum[blockIdx.x];
}

// ---------------------------------------------------------------------------
// K4: scatter edges into CSR buckets (startp[i] becomes end-of-bucket-i)
// ---------------------------------------------------------------------------
__global__ void scatter_kernel(const int* __restrict__ triple,
                               int* __restrict__ startp,
                               int* __restrict__ edge_t, int E)
{
    int i = blockIdx.x * blockDim.x + threadIdx.x;
    if (i < E) {
        int h = triple[3 * i];
        int t = triple[3 * i + 2];
        int pos = atomicAdd(&startp[h], 1);
        edge_t[pos] = t;
    }
}

// ---------------------------------------------------------------------------
// K5: per-node softmax aggregation. One wave/node. 8 edge-groups x 8 lanes;
// lane (k = lane>>3) owns dims [16k,16k+16). Scores computed in-register
// (deg<=64 fast path). bf16 x gather. Epilogue: elu(agg + x_i) from 8 lanes.
// ---------------------------------------------------------------------------
__global__ __launch_bounds__(256) void aggregate_kernel(
    const u16* __restrict__ xbf, const float* __restrict__ ssrc,
    const float* __restrict__ sdst, const int* __restrict__ endp,
    const int* __restrict__ edge_t, float* __restrict__ out, int N)
{
    const int wave = threadIdx.x >> 6;
    const int lane = threadIdx.x & 63;
    const int i = blockIdx.x * 4 + wave;
    if (i >= N) return;
    const int lo = (i == 0) ? 0 : endp[i - 1];
    const int hi = endp[i];
    const int deg = hi - lo;
    const float si = ssrc[i];
    const int k = lane >> 3;   // dim-slice 0..7
    const int g = lane & 7;    // edge-group 0..7

    float acc[16];
#pragma unroll
    for (int d = 0; d < 16; d++) acc[d] = 0.f;

    if (deg <= 64) {
        // ---- single-pass scores in registers ----
        int j = lo + lane;
        bool act = j < hi;
        int t = act ? edge_t[j] : 0;
        float e = act ? si + sdst[t] : -INFINITY;
        e = (e > 0.f) ? e : 0.2f * e;
        float m = e;
#pragma unroll
        for (int off = 32; off; off >>= 1) m = fmaxf(m, __shfl_xor(m, off));
        float p = act ? __expf(e - m) : 0.f;
        float den = p;
#pragma unroll
        for (int off = 32; off; off >>= 1) den += __shfl_xor(den, off);
        float w = (deg > 0) ? p / den : 0.f;

        // ---- 8-edge-parallel weighted gather ----
        int nit = (deg + 7) >> 3;
        for (int it = 0; it < nit; ++it) {
            int ei = it * 8 + g;
            int tt = __shfl(t, ei);
            float ww = __shfl(w, ei);
            if (ei < deg) {
                const u16x8* src = (const u16x8*)(xbf + (size_t)tt * OUT_DIM + k * 16);
                u16x8 v0 = src[0], v1 = src[1];
#pragma unroll
                for (int d = 0; d < 8; d++) {
                    acc[d]     += ww * bf2f(v0[d]);
                    acc[8 + d] += ww * bf2f(v1[d]);
                }
            }
        }
    } else {
        // ---- general path (rare): strided passes ----
        float m = -INFINITY;
        for (int j = lo + lane; j < hi; j += 64) {
            int t = edge_t[j];
            float e = si + sdst[t];
            e = (e > 0.f) ? e : 0.2f * e;
            m = fmaxf(m, e);
        }
#pragma unroll
        for (int off = 32; off; off >>= 1) m = fmaxf(m, __shfl_xor(m, off));
        float den = 0.f;
        for (int j = lo + lane; j < hi; j += 64) {
            int t = edge_t[j];
            float e = si + sdst[t];
            e = (e > 0.f) ? e : 0.2f * e;
            den += __expf(e - m);
        }
#pragma unroll
        for (int off = 32; off; off >>= 1) den += __shfl_xor(den, off);
        const float invden = 1.f / den;

        for (int jj = lo; jj < hi; jj += 8) {
            int ei = jj + g;
            if (ei < hi) {
                int tt = edge_t[ei];
                float e = si + sdst[tt];
                e = (e > 0.f) ? e : 0.2f * e;
                float ww = __expf(e - m) * invden;
                const u16x8* src = (const u16x8*)(xbf + (size_t)tt * OUT_DIM + k * 16);
                u16x8 v0 = src[0], v1 = src[1];
#pragma unroll
                for (int d = 0; d < 8; d++) {
                    acc[d]     += ww * bf2f(v0[d]);
                    acc[8 + d] += ww * bf2f(v1[d]);
                }
            }
        }
    }

    // ---- cross-group reduce (groups differ in low 3 lane bits) ----
#pragma unroll
    for (int off = 1; off < 8; off <<= 1) {
#pragma unroll
        for (int d = 0; d < 16; d++) acc[d] += __shfl_xor(acc[d], off);
    }

    // ---- epilogue from 8 lanes (g==0): elu(acc + x_i) ----
    if (g == 0) {
        const u16x8* xr = (const u16x8*)(xbf + (size_t)i * OUT_DIM + k * 16);
        u16x8 x0 = xr[0], x1 = xr[1];
        float o[16];
#pragma unroll
        for (int d = 0; d < 8; d++) {
            o[d]     = acc[d]     + bf2f(x0[d]);
            o[8 + d] = acc[8 + d] + bf2f(x1[d]);
        }
#pragma unroll
        for (int d = 0; d < 16; d++) o[d] = (o[d] > 0.f) ? o[d] : __expf(o[d]) - 1.f;
        float* dst = out + (size_t)i * OUT_DIM + k * 16;
#pragma unroll
        for (int u = 0; u < 4; u++)
            *(float4*)(dst + u * 4) = make_float4(o[u*4], o[u*4+1], o[u*4+2], o[u*4+3]);
    }
}

// ---------------------------------------------------------------------------
extern "C" void kernel_launch(void* const* d_in, const int* in_sizes, int n_in,
                              void* d_out, int out_size, void* d_ws, size_t ws_size,
                              hipStream_t stream)
{
    const float* input  = (const float*)d_in[0];
    const float* W      = (const float*)d_in[1];
    const float* a      = (const float*)d_in[2];
    const int*   triple = (const int*)d_in[3];
    const int N = in_sizes[0] / IN_DIM;
    const int E = in_sizes[3] / 3;
    float* out = (float*)d_out;

    // workspace layout
    u16*  xbf    = (u16*)d_ws;                         // N*128 bf16
    u16*  Wt     = xbf + (size_t)N * OUT_DIM;          // 16384 bf16
    float* ssrc  = (float*)(Wt + IN_DIM * OUT_DIM);    // N
    float* sdst  = ssrc + N;                           // N
    int*  counts = (int*)(sdst + N);                   // N
    int*  startp = counts + N;                         // N
    int*  bsum   = startp + N;                         // <=128
    int*  edge_t = bsum + 128;                         // E

    const int NB = (N + 1023) / 1024;

    hipMemsetAsync(counts, 0, (size_t)N * sizeof(int), stream);

    wt_kernel<<<IN_DIM, OUT_DIM, 0, stream>>>(W, Wt);
    gemm_xw_kernel<<<(N + BM - 1) / BM, 256, 0, stream>>>(input, Wt, a, xbf, ssrc, sdst, N);
    hist_kernel<<<(E + 255) / 256, 256, 0, stream>>>(triple, counts, E);
    scan_part<<<NB, 1024, 0, stream>>>(counts, bsum, N);
    scan_top<<<1, 64, 0, stream>>>(bsum, NB);
    scan_final<<<NB, 1024, 0, stream>>>(counts, bsum, startp, N);
    scatter_kernel<<<(E + 255) / 256, 256, 0, stream>>>(triple, startp, edge_t, E);
    aggregate_kernel<<<(N + 3) / 4, 256, 0, stream>>>(xbf, ssrc, sdst, startp, edge_t, out, N);
}

// Round 4
// 159.646 us; speedup vs baseline: 5.8366x; 1.9629x over previous
//
#include <hip/hip_runtime.h>
#include <hip/hip_bf16.h>
#include <math.h>

#define IN_DIM 128
#define OUT_DIM 128
#define BM 64

#define BSHIFT 9            // nodes per coarse bucket = 512
#define BNODES 512
#define CAP 12288           // pair capacity per coarse bucket region
#define EPT 16              // edges per thread in coarse_scatter

typedef short bf16x8s __attribute__((ext_vector_type(8)));
typedef float f32x4 __attribute__((ext_vector_type(4)));
typedef unsigned short u16;
typedef unsigned short u16x8 __attribute__((ext_vector_type(8)));

__device__ inline unsigned int rne_hi(float f) {
    unsigned int u = __float_as_uint(f);
    return u + 0x7fffu + ((u >> 16) & 1u);   // high 16 bits = RNE bf16
}
__device__ inline unsigned int pack_bf16x2(float lo, float hi) {
    return (rne_hi(lo) >> 16) | (rne_hi(hi) & 0xffff0000u);
}
__device__ inline float bf2f(u16 v) { return __uint_as_float(((unsigned)v) << 16); }

// ---------------------------------------------------------------------------
// K0: transpose + convert W [k][c] fp32 -> Wt bf16 [c][k]
// ---------------------------------------------------------------------------
__global__ void wt_kernel(const float* __restrict__ W, u16* __restrict__ Wt)
{
    int k = blockIdx.x;
    int c = threadIdx.x;
    float v = W[k * OUT_DIM + c];
    Wt[c * IN_DIM + k] = (u16)(rne_hi(v) >> 16);
}

// ---------------------------------------------------------------------------
// K1: x = input @ W via bf16 MFMA; writes x as bf16; fused s_src/s_dst.
// ---------------------------------------------------------------------------
__global__ __launch_bounds__(256) void gemm_xw_kernel(
    const float* __restrict__ in, const u16* __restrict__ WtG,
    const float* __restrict__ a, u16* __restrict__ xbf,
    float* __restrict__ ssrc, float* __restrict__ sdst, int N)
{
    __shared__ u16 Al[BM][IN_DIM + 8];
    __shared__ u16 Wl[OUT_DIM][IN_DIM + 8];

    const int tid  = threadIdx.x;
    const int lane = tid & 63;
    const int wave = tid >> 6;
    const int rl   = lane & 15;
    const int rgrp = lane >> 4;

    {
        int r = tid >> 1, c0 = (tid & 1) * 64;
        const uint4* src = (const uint4*)(WtG + r * IN_DIM + c0);
        uint4* dst = (uint4*)&Wl[r][c0];
#pragma unroll
        for (int u = 0; u < 8; u++) dst[u] = src[u];
    }
    const long long rowbase = (long long)blockIdx.x * BM;
    {
#pragma unroll
        for (int u = 0; u < 8; u++) {
            int idx = u * 256 + tid;
            int r = idx >> 5;
            int c = (idx & 31) * 4;
            long long gr = rowbase + r;
            if (gr >= N) gr = N - 1;
            float4 v = *(const float4*)(in + gr * IN_DIM + c);
            *(uint2*)&Al[r][c] = make_uint2(pack_bf16x2(v.x, v.y), pack_bf16x2(v.z, v.w));
        }
    }
    __syncthreads();

    f32x4 acc[8] = {};
#pragma unroll
    for (int ks = 0; ks < 4; ks++) {
        bf16x8s af = *(const bf16x8s*)&Al[wave * 16 + rl][ks * 32 + rgrp * 8];
#pragma unroll
        for (int cb = 0; cb < 8; cb++) {
            bf16x8s bf = *(const bf16x8s*)&Wl[cb * 16 + rl][ks * 32 + rgrp * 8];
            acc[cb] = __builtin_amdgcn_mfma_f32_16x16x32_bf16(af, bf, acc[cb], 0, 0, 0);
        }
    }

    float a_sv[8], a_dv[8];
#pragma unroll
    for (int cb = 0; cb < 8; cb++) {
        a_sv[cb] = a[rl + 16 * cb];
        a_dv[cb] = a[OUT_DIM + rl + 16 * cb];
    }
#pragma unroll
    for (int r = 0; r < 4; r++) {
        long long grow = rowbase + wave * 16 + rgrp * 4 + r;
        float ps = 0.f, pd = 0.f;
#pragma unroll
        for (int cb = 0; cb < 8; cb++) {
            float v = acc[cb][r];
            if (grow < N) xbf[grow * OUT_DIM + rl + 16 * cb] = (u16)(rne_hi(v) >> 16);
            ps += v * a_sv[cb];
            pd += v * a_dv[cb];
        }
#pragma unroll
        for (int off = 1; off < 16; off <<= 1) {
            ps += __shfl_xor(ps, off);
            pd += __shfl_xor(pd, off);
        }
        if (rl == 0 && grow < N) { ssrc[grow] = ps; sdst[grow] = pd; }
    }
}

// ---------------------------------------------------------------------------
// K2a: init per-bucket write cursors to region starts (b * CAP)
// ---------------------------------------------------------------------------
__global__ void init_cur_kernel(int* __restrict__ coarse_cur, int nbc)
{
    int b = blockIdx.x * blockDim.x + threadIdx.x;
    if (b < nbc) coarse_cur[b] = b * CAP;
}

// ---------------------------------------------------------------------------
// K2b: coarse scatter. Block handles 4096 edges: LDS histogram over coarse
// buckets (h>>9), one global atomic reserve per bucket, clustered pair writes.
// ---------------------------------------------------------------------------
__global__ __launch_bounds__(256) void coarse_scatter_kernel(
    const int* __restrict__ triple, int* __restrict__ coarse_cur,
    uint2* __restrict__ pairs, int E, int nbc)
{
    __shared__ int cnt[256];
    __shared__ int base[256];
    const int tid = threadIdx.x;
    const int cbase = blockIdx.x * (256 * EPT);

    cnt[tid] = 0;
    __syncthreads();

    int h[EPT], t[EPT], pos[EPT];
#pragma unroll
    for (int it = 0; it < EPT; ++it) {
        int idx = cbase + it * 256 + tid;
        if (idx < E) {
            h[it] = triple[3 * idx];
            t[it] = triple[3 * idx + 2];
            pos[it] = atomicAdd(&cnt[h[it] >> BSHIFT], 1);
        }
    }
    __syncthreads();
    if (tid < nbc && cnt[tid] > 0) base[tid] = atomicAdd(&coarse_cur[tid], cnt[tid]);
    __syncthreads();
#pragma unroll
    for (int it = 0; it < EPT; ++it) {
        int idx = cbase + it * 256 + tid;
        if (idx < E)
            pairs[base[h[it] >> BSHIFT] + pos[it]] = make_uint2((unsigned)h[it], (unsigned)t[it]);
    }
}

// ---------------------------------------------------------------------------
// K3: scan of bucket sizes -> dense CSR bucket bases (single block, nbc<=256)
// ---------------------------------------------------------------------------
__global__ __launch_bounds__(256) void bucket_scan_kernel(
    const int* __restrict__ coarse_cur, int* __restrict__ bstart, int nbc)
{
    __shared__ int s[256];
    int tid = threadIdx.x;
    int sz = (tid < nbc) ? (coarse_cur[tid] - tid * CAP) : 0;
    s[tid] = sz;
    __syncthreads();
#pragma unroll
    for (int off = 1; off < 256; off <<= 1) {
        int v = (tid >= off) ? s[tid - off] : 0;
        __syncthreads();
        s[tid] += v;
        __syncthreads();
    }
    if (tid < nbc) bstart[tid] = s[tid] - sz;
}

// ---------------------------------------------------------------------------
// K4: per-bucket CSR build. One block per coarse bucket: LDS histogram of its
// 512 nodes, LDS scan -> startp, LDS-cursor scatter of t into a local dense
// CSR window (~bucket_size*4B, L2-resident).
// ---------------------------------------------------------------------------
__global__ __launch_bounds__(512) void bucket_csr_kernel(
    const uint2* __restrict__ pairs, const int* __restrict__ coarse_cur,
    const int* __restrict__ bstart, int* __restrict__ startp,
    int* __restrict__ edge_t, int N, int E)
{
    __shared__ int cnt[BNODES];
    __shared__ int scn[BNODES];
    __shared__ int cursor[BNODES];
    const int b = blockIdx.x;
    const int tid = threadIdx.x;
    const int plo = b * CAP;
    const int psz = coarse_cur[b] - plo;
    const int obase = bstart[b];

    cnt[tid] = 0;
    __syncthreads();
    for (int j = tid; j < psz; j += BNODES)
        atomicAdd(&cnt[pairs[plo + j].x & (BNODES - 1)], 1);
    __syncthreads();
    scn[tid] = cnt[tid];
    __syncthreads();
#pragma unroll
    for (int off = 1; off < BNODES; off <<= 1) {
        int v = (tid >= off) ? scn[tid - off] : 0;
        __syncthreads();
        scn[tid] += v;
        __syncthreads();
    }
    const int excl = scn[tid] - cnt[tid];
    const int node = b * BNODES + tid;
    if (node < N) startp[node] = obase + excl;
    cursor[tid] = obase + excl;
    __syncthreads();
    for (int j = tid; j < psz; j += BNODES) {
        uint2 p = pairs[plo + j];
        int pos = atomicAdd(&cursor[p.x & (BNODES - 1)], 1);
        edge_t[pos] = (int)p.y;
    }
    if (b == 0 && tid == 0) startp[N] = E;
}

// ---------------------------------------------------------------------------
// K5: per-node softmax aggregation. One wave/node. 8 edge-groups x 8 lanes;
// lane (k = lane>>3) owns dims [16k,16k+16). Scores computed in-register
// (deg<=64 fast path). bf16 x gather. Epilogue: elu(agg + x_i) from 8 lanes.
// ---------------------------------------------------------------------------
__global__ __launch_bounds__(256) void aggregate_kernel(
    const u16* __restrict__ xbf, const float* __restrict__ ssrc,
    const float* __restrict__ sdst, const int* __restrict__ startp,
    const int* __restrict__ edge_t, float* __restrict__ out, int N)
{
    const int wave = threadIdx.x >> 6;
    const int lane = threadIdx.x & 63;
    const int i = blockIdx.x * 4 + wave;
    if (i >= N) return;
    const int lo = startp[i];
    const int hi = startp[i + 1];
    const int deg = hi - lo;
    const float si = ssrc[i];
    const int k = lane >> 3;   // dim-slice 0..7
    const int g = lane & 7;    // edge-group 0..7

    float acc[16];
#pragma unroll
    for (int d = 0; d < 16; d++) acc[d] = 0.f;

    if (deg <= 64) {
        int j = lo + lane;
        bool act = j < hi;
        int t = act ? edge_t[j] : 0;
        float e = act ? si + sdst[t] : -INFINITY;
        e = (e > 0.f) ? e : 0.2f * e;
        float m = e;
#pragma unroll
        for (int off = 32; off; off >>= 1) m = fmaxf(m, __shfl_xor(m, off));
        float p = act ? __expf(e - m) : 0.f;
        float den = p;
#pragma unroll
        for (int off = 32; off; off >>= 1) den += __shfl_xor(den, off);
        float w = (deg > 0) ? p / den : 0.f;

        int nit = (deg + 7) >> 3;
        for (int it = 0; it < nit; ++it) {
            int ei = it * 8 + g;
            int tt = __shfl(t, ei);
            float ww = __shfl(w, ei);
            if (ei < deg) {
                const u16x8* src = (const u16x8*)(xbf + (size_t)tt * OUT_DIM + k * 16);
                u16x8 v0 = src[0], v1 = src[1];
#pragma unroll
                for (int d = 0; d < 8; d++) {
                    acc[d]     += ww * bf2f(v0[d]);
                    acc[8 + d] += ww * bf2f(v1[d]);
                }
            }
        }
    } else {
        float m = -INFINITY;
        for (int j = lo + lane; j < hi; j += 64) {
            int t = edge_t[j];
            float e = si + sdst[t];
            e = (e > 0.f) ? e : 0.2f * e;
            m = fmaxf(m, e);
        }
#pragma unroll
        for (int off = 32; off; off >>= 1) m = fmaxf(m, __shfl_xor(m, off));
        float den = 0.f;
        for (int j = lo + lane; j < hi; j += 64) {
            int t = edge_t[j];
            float e = si + sdst[t];
            e = (e > 0.f) ? e : 0.2f * e;
            den += __expf(e - m);
        }
#pragma unroll
        for (int off = 32; off; off >>= 1) den += __shfl_xor(den, off);
        const float invden = 1.f / den;

        for (int jj = lo; jj < hi; jj += 8) {
            int ei = jj + g;
            if (ei < hi) {
                int tt = edge_t[ei];
                float e = si + sdst[tt];
                e = (e > 0.f) ? e : 0.2f * e;
                float ww = __expf(e - m) * invden;
                const u16x8* src = (const u16x8*)(xbf + (size_t)tt * OUT_DIM + k * 16);
                u16x8 v0 = src[0], v1 = src[1];
#pragma unroll
                for (int d = 0; d < 8; d++) {
                    acc[d]     += ww * bf2f(v0[d]);
                    acc[8 + d] += ww * bf2f(v1[d]);
                }
            }
        }
    }

#pragma unroll
    for (int off = 1; off < 8; off <<= 1) {
#pragma unroll
        for (int d = 0; d < 16; d++) acc[d] += __shfl_xor(acc[d], off);
    }

    if (g == 0) {
        const u16x8* xr = (const u16x8*)(xbf + (size_t)i * OUT_DIM + k * 16);
        u16x8 x0 = xr[0], x1 = xr[1];
        float o[16];
#pragma unroll
        for (int d = 0; d < 8; d++) {
            o[d]     = acc[d]     + bf2f(x0[d]);
            o[8 + d] = acc[8 + d] + bf2f(x1[d]);
        }
#pragma unroll
        for (int d = 0; d < 16; d++) o[d] = (o[d] > 0.f) ? o[d] : __expf(o[d]) - 1.f;
        float* dst = out + (size_t)i * OUT_DIM + k * 16;
#pragma unroll
        for (int u = 0; u < 4; u++)
            *(float4*)(dst + u * 4) = make_float4(o[u*4], o[u*4+1], o[u*4+2], o[u*4+3]);
    }
}

// ---------------------------------------------------------------------------
extern "C" void kernel_launch(void* const* d_in, const int* in_sizes, int n_in,
                              void* d_out, int out_size, void* d_ws, size_t ws_size,
                              hipStream_t stream)
{
    const float* input  = (const float*)d_in[0];
    const float* W      = (const float*)d_in[1];
    const float* a      = (const float*)d_in[2];
    const int*   triple = (const int*)d_in[3];
    const int N = in_sizes[0] / IN_DIM;
    const int E = in_sizes[3] / 3;
    float* out = (float*)d_out;

    const int NBC = (N + BNODES - 1) >> BSHIFT;   // coarse buckets (<=256)

    // workspace layout
    char* p = (char*)d_ws;
    u16* xbf = (u16*)p;                 p += (size_t)N * OUT_DIM * sizeof(u16);
    u16* Wt  = (u16*)p;                 p += (size_t)IN_DIM * OUT_DIM * sizeof(u16);
    float* ssrc = (float*)p;            p += (size_t)N * sizeof(float);
    float* sdst = (float*)p;            p += (size_t)N * sizeof(float);
    int* startp = (int*)p;              p += (size_t)(N + 1) * sizeof(int);
    int* coarse_cur = (int*)p;          p += 256 * sizeof(int);
    int* bstart = (int*)p;              p += 256 * sizeof(int);
    int* edge_t = (int*)p;              p += (size_t)E * sizeof(int);
    p = (char*)(((size_t)p + 15) & ~(size_t)15);
    uint2* pairs = (uint2*)p;           // NBC * CAP * 8 bytes

    const int NCHUNK = (E + 256 * EPT - 1) / (256 * EPT);

    wt_kernel<<<IN_DIM, OUT_DIM, 0, stream>>>(W, Wt);
    gemm_xw_kernel<<<(N + BM - 1) / BM, 256, 0, stream>>>(input, Wt, a, xbf, ssrc, sdst, N);
    init_cur_kernel<<<1, 256, 0, stream>>>(coarse_cur, NBC);
    coarse_scatter_kernel<<<NCHUNK, 256, 0, stream>>>(triple, coarse_cur, pairs, E, NBC);
    bucket_scan_kernel<<<1, 256, 0, stream>>>(coarse_cur, bstart, NBC);
    bucket_csr_kernel<<<NBC, BNODES, 0, stream>>>(pairs, coarse_cur, bstart, startp, edge_t, N, E);
    aggregate_kernel<<<(N + 3) / 4, 256, 0, stream>>>(xbf, ssrc, sdst, startp, edge_t, out, N);
}